// Round 1
// baseline (468.373 us; speedup 1.0000x reference)
//
#include <hip/hip_runtime.h>
#include <hip/hip_bf16.h>

typedef __attribute__((ext_vector_type(8))) short s16x8;
typedef __attribute__((ext_vector_type(4))) float f32x4;

#define T_TOK 8192
#define H_DIM 512
#define I_DIM 1024

static __device__ __forceinline__ unsigned short f2bf(float f){
  unsigned int b = __builtin_bit_cast(unsigned int, f);
  b += 0x7FFFu + ((b >> 16) & 1u);           // round-to-nearest-even
  return (unsigned short)(b >> 16);
}

// ---- x fp32 -> bf16 (4.19M elems) ----
__global__ void cvt_x_kernel(const float* __restrict__ in, unsigned short* __restrict__ out){
  int i = (blockIdx.x * 256 + threadIdx.x) * 4;
  float4 v = *reinterpret_cast<const float4*>(in + i);
  ushort4 o;
  o.x = f2bf(v.x); o.y = f2bf(v.y); o.z = f2bf(v.z); o.w = f2bf(v.w);
  *reinterpret_cast<ushort4*>(out + i) = o;
}

// ---- per-expert transpose + convert: in [E][R][C] f32 -> out [E][C][R] bf16 ----
__global__ void transpose_cvt(const float* __restrict__ in, unsigned short* __restrict__ out,
                              int R, int C){
  __shared__ unsigned short tile[64][72];
  int e = blockIdx.z;
  const float* src = in + (size_t)e * R * C;
  unsigned short* dst = out + (size_t)e * R * C;
  int r0 = blockIdx.y * 64, c0 = blockIdx.x * 64;
  int tr = threadIdx.x >> 4;           // 0..15
  int tc = (threadIdx.x & 15) * 4;     // 0..60
  #pragma unroll
  for (int i = 0; i < 4; i++){
    int r = tr + i * 16;
    float4 v = *reinterpret_cast<const float4*>(src + (size_t)(r0 + r) * C + c0 + tc);
    tile[tc + 0][r] = f2bf(v.x);
    tile[tc + 1][r] = f2bf(v.y);
    tile[tc + 2][r] = f2bf(v.z);
    tile[tc + 3][r] = f2bf(v.w);
  }
  __syncthreads();
  #pragma unroll
  for (int i = 0; i < 4; i++){
    int cl = tr + i * 16;              // col of original = row of transposed
    ushort4 o;
    o.x = tile[cl][tc + 0]; o.y = tile[cl][tc + 1];
    o.z = tile[cl][tc + 2]; o.w = tile[cl][tc + 3];
    *reinterpret_cast<ushort4*>(dst + (size_t)(c0 + cl) * R + r0 + tc) = o;
  }
}

// ---- router: logits (fp32), softmax, top-2, scatter to per-expert lists ----
__global__ void router_kernel(const float* __restrict__ x, const float* __restrict__ gw,
                              float* __restrict__ logits_out,
                              int* __restrict__ cnt, int* __restrict__ tok,
                              float* __restrict__ wgt){
  int wave = threadIdx.x >> 6;
  int lane = threadIdx.x & 63;
  int t = blockIdx.x * 4 + wave;
  const float* xr = x + (size_t)t * H_DIM;
  float xv[8];
  *reinterpret_cast<float4*>(&xv[0]) = *reinterpret_cast<const float4*>(xr + lane * 8);
  *reinterpret_cast<float4*>(&xv[4]) = *reinterpret_cast<const float4*>(xr + lane * 8 + 4);
  float l[8];
  #pragma unroll
  for (int e = 0; e < 8; e++){
    const float* g = gw + e * H_DIM + lane * 8;
    float4 g0 = *reinterpret_cast<const float4*>(g);
    float4 g1 = *reinterpret_cast<const float4*>(g + 4);
    float s = xv[0]*g0.x + xv[1]*g0.y + xv[2]*g0.z + xv[3]*g0.w
            + xv[4]*g1.x + xv[5]*g1.y + xv[6]*g1.z + xv[7]*g1.w;
    #pragma unroll
    for (int o = 32; o >= 1; o >>= 1) s += __shfl_xor(s, o);
    l[e] = s;
  }
  if (lane == 0){
    float m = l[0];
    #pragma unroll
    for (int e = 1; e < 8; e++) m = fmaxf(m, l[e]);
    float p[8]; float Z = 0.f;
    #pragma unroll
    for (int e = 0; e < 8; e++){ p[e] = expf(l[e] - m); Z += p[e]; }
    int a = 0;
    #pragma unroll
    for (int e = 1; e < 8; e++) if (p[e] > p[a]) a = e;   // earliest max: matches top_k
    int b = (a == 0) ? 1 : 0;
    #pragma unroll
    for (int e = 0; e < 8; e++) if (e != a && p[e] > p[b]) b = e;
    float pa = p[a] / Z, pb = p[b] / Z;
    float inv = 0.5f / (pa + pb + 1e-20f);                // norm_topk + /TOP_K
    #pragma unroll
    for (int e = 0; e < 8; e++) logits_out[(size_t)t * 8 + e] = l[e];
    int sa = atomicAdd(&cnt[a], 1);
    tok[a * T_TOK + sa] = t; wgt[a * T_TOK + sa] = pa * inv;
    int sb = atomicAdd(&cnt[b], 1);
    tok[b * T_TOK + sb] = t; wgt[b * T_TOK + sb] = pb * inv;
  }
}

__global__ void prefix_kernel(const int* __restrict__ cnt, int* __restrict__ off){
  if (threadIdx.x == 0){
    int s = 0;
    for (int e = 0; e < 8; e++){ off[e] = s; s += cnt[e]; }
  }
}

// ---- GEMM1: h = relu(gather(xb) @ w1t^T + b1), bf16 out ----
__global__ __launch_bounds__(256) void gemm1_kernel(
    const unsigned short* __restrict__ xb, const unsigned short* __restrict__ w1t,
    const float* __restrict__ b1,
    const int* __restrict__ cnt, const int* __restrict__ off,
    const int* __restrict__ tok,
    unsigned short* __restrict__ h_buf){
  int e  = blockIdx.x >> 6;
  int tm = blockIdx.x & 63;
  int n_e = cnt[e];
  int base = tm * 128;
  if (base >= n_e) return;
  int n0 = blockIdx.y * 128;

  __shared__ unsigned short As[128 * 72];
  __shared__ unsigned short Bs[128 * 72];
  __shared__ int tok_s[128];

  int tid = threadIdx.x;
  if (tid < 128){
    int gr = base + tid;
    tok_s[tid] = (gr < n_e) ? tok[e * T_TOK + gr] : tok[e * T_TOK];
  }
  __syncthreads();

  int lane = tid & 63, wid = tid >> 6;
  int wm = (wid >> 1) * 64, wn = (wid & 1) * 64;
  int rfrag = lane & 15;
  int koff  = (lane >> 4) * 8;

  f32x4 acc[4][4] = {};
  const unsigned short* Bg = w1t + ((size_t)e * I_DIM + n0) * H_DIM;

  for (int k0 = 0; k0 < H_DIM; k0 += 64){
    #pragma unroll
    for (int i = 0; i < 4; i++){
      int c = tid + i * 256;
      int r = c >> 3, cc = (c & 7) * 8;
      int4 va = *reinterpret_cast<const int4*>(xb + (size_t)tok_s[r] * H_DIM + k0 + cc);
      *reinterpret_cast<int4*>(&As[r * 72 + cc]) = va;
      int4 vb = *reinterpret_cast<const int4*>(Bg + (size_t)r * H_DIM + k0 + cc);
      *reinterpret_cast<int4*>(&Bs[r * 72 + cc]) = vb;
    }
    __syncthreads();
    #pragma unroll
    for (int kk = 0; kk < 2; kk++){
      s16x8 af[4], bfr[4];
      #pragma unroll
      for (int fm = 0; fm < 4; fm++)
        af[fm] = *reinterpret_cast<const s16x8*>(&As[(wm + fm * 16 + rfrag) * 72 + kk * 32 + koff]);
      #pragma unroll
      for (int fn = 0; fn < 4; fn++)
        bfr[fn] = *reinterpret_cast<const s16x8*>(&Bs[(wn + fn * 16 + rfrag) * 72 + kk * 32 + koff]);
      #pragma unroll
      for (int fm = 0; fm < 4; fm++){
        #pragma unroll
        for (int fn = 0; fn < 4; fn++)
          acc[fm][fn] = __builtin_amdgcn_mfma_f32_16x16x32_bf16(af[fm], bfr[fn], acc[fm][fn], 0, 0, 0);
      }
    }
    __syncthreads();
  }

  int offe = off[e];
  int rbase = wm + (lane >> 4) * 4;
  #pragma unroll
  for (int fm = 0; fm < 4; fm++){
    #pragma unroll
    for (int j = 0; j < 4; j++){
      int gr = base + rbase + fm * 16 + j;
      if (gr < n_e){
        #pragma unroll
        for (int fn = 0; fn < 4; fn++){
          int col = n0 + wn + fn * 16 + rfrag;
          float h = acc[fm][fn][j] + b1[e * I_DIM + col];
          h_buf[(size_t)(offe + gr) * I_DIM + col] = f2bf(fmaxf(h, 0.f));
        }
      }
    }
  }
}

// ---- GEMM2: y = h @ w2t^T + b2; out[t] += w * y (atomic scatter) ----
__global__ __launch_bounds__(256) void gemm2_kernel(
    const unsigned short* __restrict__ h_buf, const unsigned short* __restrict__ w2t,
    const float* __restrict__ b2,
    const int* __restrict__ cnt, const int* __restrict__ off,
    const int* __restrict__ tok, const float* __restrict__ wgt,
    float* __restrict__ out){
  int e  = blockIdx.x >> 6;
  int tm = blockIdx.x & 63;
  int n_e = cnt[e];
  int base = tm * 128;
  if (base >= n_e) return;
  int n0 = blockIdx.y * 128;

  __shared__ unsigned short As[128 * 72];
  __shared__ unsigned short Bs[128 * 72];
  __shared__ int tok_s[128];
  __shared__ float wgt_s[128];

  int tid = threadIdx.x;
  int offe = off[e];
  if (tid < 128){
    int gr = base + tid;
    int gi = (gr < n_e) ? gr : (n_e - 1);
    tok_s[tid] = tok[e * T_TOK + gi];
    wgt_s[tid] = wgt[e * T_TOK + gi];
  }
  __syncthreads();

  int lane = tid & 63, wid = tid >> 6;
  int wm = (wid >> 1) * 64, wn = (wid & 1) * 64;
  int rfrag = lane & 15;
  int koff  = (lane >> 4) * 8;

  f32x4 acc[4][4] = {};
  const unsigned short* Ag = h_buf + (size_t)(offe + base) * I_DIM;
  const unsigned short* Bg = w2t + ((size_t)e * H_DIM + n0) * I_DIM;

  for (int k0 = 0; k0 < I_DIM; k0 += 64){
    #pragma unroll
    for (int i = 0; i < 4; i++){
      int c = tid + i * 256;
      int r = c >> 3, cc = (c & 7) * 8;
      int4 va = *reinterpret_cast<const int4*>(Ag + (size_t)r * I_DIM + k0 + cc);
      *reinterpret_cast<int4*>(&As[r * 72 + cc]) = va;
      int4 vb = *reinterpret_cast<const int4*>(Bg + (size_t)r * I_DIM + k0 + cc);
      *reinterpret_cast<int4*>(&Bs[r * 72 + cc]) = vb;
    }
    __syncthreads();
    #pragma unroll
    for (int kk = 0; kk < 2; kk++){
      s16x8 af[4], bfr[4];
      #pragma unroll
      for (int fm = 0; fm < 4; fm++)
        af[fm] = *reinterpret_cast<const s16x8*>(&As[(wm + fm * 16 + rfrag) * 72 + kk * 32 + koff]);
      #pragma unroll
      for (int fn = 0; fn < 4; fn++)
        bfr[fn] = *reinterpret_cast<const s16x8*>(&Bs[(wn + fn * 16 + rfrag) * 72 + kk * 32 + koff]);
      #pragma unroll
      for (int fm = 0; fm < 4; fm++){
        #pragma unroll
        for (int fn = 0; fn < 4; fn++)
          acc[fm][fn] = __builtin_amdgcn_mfma_f32_16x16x32_bf16(af[fm], bfr[fn], acc[fm][fn], 0, 0, 0);
      }
    }
    __syncthreads();
  }

  int rbase = wm + (lane >> 4) * 4;
  #pragma unroll
  for (int fm = 0; fm < 4; fm++){
    #pragma unroll
    for (int j = 0; j < 4; j++){
      int row_l = rbase + fm * 16 + j;
      int gr = base + row_l;
      if (gr < n_e){
        int t = tok_s[row_l];
        float wv = wgt_s[row_l];
        #pragma unroll
        for (int fn = 0; fn < 4; fn++){
          int col = n0 + wn + fn * 16 + rfrag;
          float y = acc[fm][fn][j] + b2[e * H_DIM + col];
          atomicAdd(out + (size_t)t * H_DIM + col, wv * y);
        }
      }
    }
  }
}

extern "C" void kernel_launch(void* const* d_in, const int* in_sizes, int n_in,
                              void* d_out, int out_size, void* d_ws, size_t ws_size,
                              hipStream_t stream){
  const float* x  = (const float*)d_in[0];
  const float* gw = (const float*)d_in[1];
  const float* w1 = (const float*)d_in[2];
  const float* b1 = (const float*)d_in[3];
  const float* w2 = (const float*)d_in[4];
  const float* b2 = (const float*)d_in[5];
  float* out = (float*)d_out;

  char* ws = (char*)d_ws;
  int*   cnt = (int*)(ws);
  int*   off = (int*)(ws + 32);
  int*   tok = (int*)(ws + 64);                               // 8*8192 ints = 256 KB
  float* wgt = (float*)(ws + 64 + 262144);                    // 256 KB
  unsigned short* xb    = (unsigned short*)(ws + 524352);     // 8 MB
  unsigned short* w1t   = (unsigned short*)(ws + 8912960);    // 8 MB  [E][I][H]
  unsigned short* w2t   = (unsigned short*)(ws + 17301568);   // 8 MB  [E][H][I]
  unsigned short* h_buf = (unsigned short*)(ws + 25690176);   // (16384+128)*1024*2 = 33.8 MB

  hipMemsetAsync(d_out, 0, (size_t)out_size * 4, stream);
  hipMemsetAsync(cnt, 0, 64, stream);

  cvt_x_kernel<<<4096, 256, 0, stream>>>(x, xb);
  transpose_cvt<<<dim3(16, 8, 8), 256, 0, stream>>>(w1, w1t, 512, 1024);
  transpose_cvt<<<dim3(8, 16, 8), 256, 0, stream>>>(w2, w2t, 1024, 512);

  float* logits_out = out + (size_t)T_TOK * H_DIM;
  router_kernel<<<2048, 256, 0, stream>>>(x, gw, logits_out, cnt, tok, wgt);
  prefix_kernel<<<1, 64, 0, stream>>>(cnt, off);

  gemm1_kernel<<<dim3(512, 8), 256, 0, stream>>>(xb, w1t, b1, cnt, off, tok, h_buf);
  gemm2_kernel<<<dim3(512, 4), 256, 0, stream>>>(h_buf, w2t, b2, cnt, off, tok, wgt, out);
}

// Round 3
// 288.108 us; speedup vs baseline: 1.6257x; 1.6257x over previous
//
#include <hip/hip_runtime.h>
#include <hip/hip_bf16.h>

typedef __attribute__((ext_vector_type(8))) short s16x8;
typedef __attribute__((ext_vector_type(4))) float f32x4;

#define T_TOK 8192
#define H_DIM 512
#define I_DIM 1024

static __device__ __forceinline__ unsigned short f2bf(float f){
  unsigned int b = __builtin_bit_cast(unsigned int, f);
  b += 0x7FFFu + ((b >> 16) & 1u);           // round-to-nearest-even
  return (unsigned short)(b >> 16);
}

// ---- x fp32 -> bf16 (4.19M elems) ----
__global__ void cvt_x_kernel(const float* __restrict__ in, unsigned short* __restrict__ out){
  int i = (blockIdx.x * 256 + threadIdx.x) * 4;
  float4 v = *reinterpret_cast<const float4*>(in + i);
  ushort4 o;
  o.x = f2bf(v.x); o.y = f2bf(v.y); o.z = f2bf(v.z); o.w = f2bf(v.w);
  *reinterpret_cast<ushort4*>(out + i) = o;
}

// ---- per-expert transpose + convert: in [E][R][C] f32 -> out [E][C][R] bf16 ----
__global__ void transpose_cvt(const float* __restrict__ in, unsigned short* __restrict__ out,
                              int R, int C){
  __shared__ unsigned short tile[64][72];
  int e = blockIdx.z;
  const float* src = in + (size_t)e * R * C;
  unsigned short* dst = out + (size_t)e * R * C;
  int r0 = blockIdx.y * 64, c0 = blockIdx.x * 64;
  int tr = threadIdx.x >> 4;           // 0..15
  int tc = (threadIdx.x & 15) * 4;     // 0..60
  #pragma unroll
  for (int i = 0; i < 4; i++){
    int r = tr + i * 16;
    float4 v = *reinterpret_cast<const float4*>(src + (size_t)(r0 + r) * C + c0 + tc);
    tile[tc + 0][r] = f2bf(v.x);
    tile[tc + 1][r] = f2bf(v.y);
    tile[tc + 2][r] = f2bf(v.z);
    tile[tc + 3][r] = f2bf(v.w);
  }
  __syncthreads();
  #pragma unroll
  for (int i = 0; i < 4; i++){
    int cl = tr + i * 16;              // col of original = row of transposed
    ushort4 o;
    o.x = tile[cl][tc + 0]; o.y = tile[cl][tc + 1];
    o.z = tile[cl][tc + 2]; o.w = tile[cl][tc + 3];
    *reinterpret_cast<ushort4*>(dst + (size_t)(c0 + cl) * R + r0 + tc) = o;
  }
}

// ---- router stage 1: logits (fp32) + top-2 selection. NO atomics. ----
__global__ void router_logits_kernel(const float* __restrict__ x, const float* __restrict__ gw,
                                     float* __restrict__ logits_out,
                                     int* __restrict__ eab, float* __restrict__ wab){
  int wave = threadIdx.x >> 6;
  int lane = threadIdx.x & 63;
  int t = blockIdx.x * 4 + wave;
  const float* xr = x + (size_t)t * H_DIM;
  float xv[8];
  *reinterpret_cast<float4*>(&xv[0]) = *reinterpret_cast<const float4*>(xr + lane * 8);
  *reinterpret_cast<float4*>(&xv[4]) = *reinterpret_cast<const float4*>(xr + lane * 8 + 4);
  float l[8];
  #pragma unroll
  for (int e = 0; e < 8; e++){
    const float* g = gw + e * H_DIM + lane * 8;
    float4 g0 = *reinterpret_cast<const float4*>(g);
    float4 g1 = *reinterpret_cast<const float4*>(g + 4);
    float s = xv[0]*g0.x + xv[1]*g0.y + xv[2]*g0.z + xv[3]*g0.w
            + xv[4]*g1.x + xv[5]*g1.y + xv[6]*g1.z + xv[7]*g1.w;
    #pragma unroll
    for (int o = 32; o >= 1; o >>= 1) s += __shfl_xor(s, o);
    l[e] = s;
  }
  if (lane == 0){
    float4 L0 = make_float4(l[0], l[1], l[2], l[3]);
    float4 L1 = make_float4(l[4], l[5], l[6], l[7]);
    *reinterpret_cast<float4*>(logits_out + (size_t)t * 8)     = L0;
    *reinterpret_cast<float4*>(logits_out + (size_t)t * 8 + 4) = L1;
    float m = l[0];
    #pragma unroll
    for (int e = 1; e < 8; e++) m = fmaxf(m, l[e]);
    float p[8]; float Z = 0.f;
    #pragma unroll
    for (int e = 0; e < 8; e++){ p[e] = expf(l[e] - m); Z += p[e]; }
    int a = 0;
    #pragma unroll
    for (int e = 1; e < 8; e++) if (p[e] > p[a]) a = e;   // earliest max: matches top_k
    int b = (a == 0) ? 1 : 0;
    #pragma unroll
    for (int e = 0; e < 8; e++) if (e != a && p[e] > p[b]) b = e;
    float pa = p[a] / Z, pb = p[b] / Z;
    float inv = 0.5f / (pa + pb + 1e-20f);                // norm_topk + /TOP_K
    eab[t] = a | (b << 8);
    *reinterpret_cast<float2*>(wab + (size_t)t * 2) = make_float2(pa * inv, pb * inv);
  }
}

// ---- router stage 2: ballot-aggregated scatter into per-expert lists ----
__global__ __launch_bounds__(256) void scatter_kernel(
    const int* __restrict__ eab, const float* __restrict__ wab,
    int* __restrict__ cnt, int* __restrict__ tok, float* __restrict__ wgt){
  __shared__ int wcnt[8][8];    // [wave*2+slot][expert]
  __shared__ int lbase[8][8];
  __shared__ int gbase[8];
  int tid = threadIdx.x;
  int wave = tid >> 6, lane = tid & 63;
  int t = blockIdx.x * 256 + tid;
  int ee = eab[t];
  int ea = ee & 0xff, eb = ee >> 8;
  float2 wv = *reinterpret_cast<const float2*>(wab + (size_t)t * 2);
  unsigned long long mlt = (1ull << lane) - 1ull;
  int rankA = 0, rankB = 0;
  #pragma unroll
  for (int e = 0; e < 8; e++){
    unsigned long long mA = __ballot(ea == e);
    unsigned long long mB = __ballot(eb == e);
    if (ea == e) rankA = __popcll(mA & mlt);
    if (eb == e) rankB = __popcll(mB & mlt);
    if (lane == 0){
      wcnt[wave * 2 + 0][e] = __popcll(mA);
      wcnt[wave * 2 + 1][e] = __popcll(mB);
    }
  }
  __syncthreads();
  if (tid < 8){                  // thread tid owns expert tid
    int s = 0;
    #pragma unroll
    for (int w = 0; w < 8; w++){ lbase[w][tid] = s; s += wcnt[w][tid]; }
    gbase[tid] = atomicAdd(&cnt[tid], s);
  }
  __syncthreads();
  int ia = gbase[ea] + lbase[wave * 2 + 0][ea] + rankA;
  tok[ea * T_TOK + ia] = t; wgt[ea * T_TOK + ia] = wv.x;
  int ib = gbase[eb] + lbase[wave * 2 + 1][eb] + rankB;
  tok[eb * T_TOK + ib] = t; wgt[eb * T_TOK + ib] = wv.y;
}

__global__ void prefix_kernel(const int* __restrict__ cnt, int* __restrict__ off){
  if (threadIdx.x == 0){
    int s = 0;
    for (int e = 0; e < 8; e++){ off[e] = s; s += cnt[e]; }
  }
}

// ---- GEMM1: h = relu(gather(xb) @ w1t^T + b1), bf16 out ----
__global__ __launch_bounds__(256) void gemm1_kernel(
    const unsigned short* __restrict__ xb, const unsigned short* __restrict__ w1t,
    const float* __restrict__ b1,
    const int* __restrict__ cnt, const int* __restrict__ off,
    const int* __restrict__ tok,
    unsigned short* __restrict__ h_buf){
  int e  = blockIdx.x >> 6;
  int tm = blockIdx.x & 63;
  int n_e = cnt[e];
  int base = tm * 128;
  if (base >= n_e) return;
  int n0 = blockIdx.y * 128;

  __shared__ unsigned short As[128 * 72];
  __shared__ unsigned short Bs[128 * 72];
  __shared__ int tok_s[128];

  int tid = threadIdx.x;
  if (tid < 128){
    int gr = base + tid;
    tok_s[tid] = (gr < n_e) ? tok[e * T_TOK + gr] : tok[e * T_TOK];
  }
  __syncthreads();

  int lane = tid & 63, wid = tid >> 6;
  int wm = (wid >> 1) * 64, wn = (wid & 1) * 64;
  int rfrag = lane & 15;
  int koff  = (lane >> 4) * 8;

  f32x4 acc[4][4] = {};
  const unsigned short* Bg = w1t + ((size_t)e * I_DIM + n0) * H_DIM;

  for (int k0 = 0; k0 < H_DIM; k0 += 64){
    #pragma unroll
    for (int i = 0; i < 4; i++){
      int c = tid + i * 256;
      int r = c >> 3, cc = (c & 7) * 8;
      int4 va = *reinterpret_cast<const int4*>(xb + (size_t)tok_s[r] * H_DIM + k0 + cc);
      *reinterpret_cast<int4*>(&As[r * 72 + cc]) = va;
      int4 vb = *reinterpret_cast<const int4*>(Bg + (size_t)r * H_DIM + k0 + cc);
      *reinterpret_cast<int4*>(&Bs[r * 72 + cc]) = vb;
    }
    __syncthreads();
    #pragma unroll
    for (int kk = 0; kk < 2; kk++){
      s16x8 af[4], bfr[4];
      #pragma unroll
      for (int fm = 0; fm < 4; fm++)
        af[fm] = *reinterpret_cast<const s16x8*>(&As[(wm + fm * 16 + rfrag) * 72 + kk * 32 + koff]);
      #pragma unroll
      for (int fn = 0; fn < 4; fn++)
        bfr[fn] = *reinterpret_cast<const s16x8*>(&Bs[(wn + fn * 16 + rfrag) * 72 + kk * 32 + koff]);
      #pragma unroll
      for (int fm = 0; fm < 4; fm++){
        #pragma unroll
        for (int fn = 0; fn < 4; fn++)
          acc[fm][fn] = __builtin_amdgcn_mfma_f32_16x16x32_bf16(af[fm], bfr[fn], acc[fm][fn], 0, 0, 0);
      }
    }
    __syncthreads();
  }

  int offe = off[e];
  int rbase = wm + (lane >> 4) * 4;
  #pragma unroll
  for (int fm = 0; fm < 4; fm++){
    #pragma unroll
    for (int j = 0; j < 4; j++){
      int gr = base + rbase + fm * 16 + j;
      if (gr < n_e){
        #pragma unroll
        for (int fn = 0; fn < 4; fn++){
          int col = n0 + wn + fn * 16 + rfrag;
          float h = acc[fm][fn][j] + b1[e * I_DIM + col];
          h_buf[(size_t)(offe + gr) * I_DIM + col] = f2bf(fmaxf(h, 0.f));
        }
      }
    }
  }
}

// ---- GEMM2: y = h @ w2t^T + b2; out[t] += w * y (atomic scatter) ----
__global__ __launch_bounds__(256) void gemm2_kernel(
    const unsigned short* __restrict__ h_buf, const unsigned short* __restrict__ w2t,
    const float* __restrict__ b2,
    const int* __restrict__ cnt, const int* __restrict__ off,
    const int* __restrict__ tok, const float* __restrict__ wgt,
    float* __restrict__ out){
  int e  = blockIdx.x >> 6;
  int tm = blockIdx.x & 63;
  int n_e = cnt[e];
  int base = tm * 128;
  if (base >= n_e) return;
  int n0 = blockIdx.y * 128;

  __shared__ unsigned short As[128 * 72];
  __shared__ unsigned short Bs[128 * 72];
  __shared__ int tok_s[128];
  __shared__ float wgt_s[128];

  int tid = threadIdx.x;
  int offe = off[e];
  if (tid < 128){
    int gr = base + tid;
    int gi = (gr < n_e) ? gr : (n_e - 1);
    tok_s[tid] = tok[e * T_TOK + gi];
    wgt_s[tid] = wgt[e * T_TOK + gi];
  }
  __syncthreads();

  int lane = tid & 63, wid = tid >> 6;
  int wm = (wid >> 1) * 64, wn = (wid & 1) * 64;
  int rfrag = lane & 15;
  int koff  = (lane >> 4) * 8;

  f32x4 acc[4][4] = {};
  const unsigned short* Ag = h_buf + (size_t)(offe + base) * I_DIM;
  const unsigned short* Bg = w2t + ((size_t)e * H_DIM + n0) * I_DIM;

  for (int k0 = 0; k0 < I_DIM; k0 += 64){
    #pragma unroll
    for (int i = 0; i < 4; i++){
      int c = tid + i * 256;
      int r = c >> 3, cc = (c & 7) * 8;
      int4 va = *reinterpret_cast<const int4*>(Ag + (size_t)r * I_DIM + k0 + cc);
      *reinterpret_cast<int4*>(&As[r * 72 + cc]) = va;
      int4 vb = *reinterpret_cast<const int4*>(Bg + (size_t)r * I_DIM + k0 + cc);
      *reinterpret_cast<int4*>(&Bs[r * 72 + cc]) = vb;
    }
    __syncthreads();
    #pragma unroll
    for (int kk = 0; kk < 2; kk++){
      s16x8 af[4], bfr[4];
      #pragma unroll
      for (int fm = 0; fm < 4; fm++)
        af[fm] = *reinterpret_cast<const s16x8*>(&As[(wm + fm * 16 + rfrag) * 72 + kk * 32 + koff]);
      #pragma unroll
      for (int fn = 0; fn < 4; fn++)
        bfr[fn] = *reinterpret_cast<const s16x8*>(&Bs[(wn + fn * 16 + rfrag) * 72 + kk * 32 + koff]);
      #pragma unroll
      for (int fm = 0; fm < 4; fm++){
        #pragma unroll
        for (int fn = 0; fn < 4; fn++)
          acc[fm][fn] = __builtin_amdgcn_mfma_f32_16x16x32_bf16(af[fm], bfr[fn], acc[fm][fn], 0, 0, 0);
      }
    }
    __syncthreads();
  }

  int rbase = wm + (lane >> 4) * 4;
  #pragma unroll
  for (int fm = 0; fm < 4; fm++){
    #pragma unroll
    for (int j = 0; j < 4; j++){
      int row_l = rbase + fm * 16 + j;
      int gr = base + row_l;
      if (gr < n_e){
        int t = tok_s[row_l];
        float wv = wgt_s[row_l];
        #pragma unroll
        for (int fn = 0; fn < 4; fn++){
          int col = n0 + wn + fn * 16 + rfrag;
          float y = acc[fm][fn][j] + b2[e * H_DIM + col];
          atomicAdd(out + (size_t)t * H_DIM + col, wv * y);
        }
      }
    }
  }
}

extern "C" void kernel_launch(void* const* d_in, const int* in_sizes, int n_in,
                              void* d_out, int out_size, void* d_ws, size_t ws_size,
                              hipStream_t stream){
  const float* x  = (const float*)d_in[0];
  const float* gw = (const float*)d_in[1];
  const float* w1 = (const float*)d_in[2];
  const float* b1 = (const float*)d_in[3];
  const float* w2 = (const float*)d_in[4];
  const float* b2 = (const float*)d_in[5];
  float* out = (float*)d_out;

  char* ws = (char*)d_ws;
  int*   cnt = (int*)(ws);
  int*   off = (int*)(ws + 32);
  int*   tok = (int*)(ws + 64);                               // 8*8192 ints = 256 KB
  float* wgt = (float*)(ws + 64 + 262144);                    // 256 KB
  unsigned short* xb    = (unsigned short*)(ws + 524352);     // 8 MB
  unsigned short* w1t   = (unsigned short*)(ws + 8912960);    // 8 MB  [E][I][H]
  unsigned short* w2t   = (unsigned short*)(ws + 17301568);   // 8 MB  [E][H][I]
  unsigned short* h_buf = (unsigned short*)(ws + 25690176);   // 16384*1024*2 = 32 MB
  int*   eab = (int*)(ws + 59244608);                         // 32 KB
  float* wab = (float*)(ws + 59277376);                       // 64 KB

  hipMemsetAsync(d_out, 0, (size_t)out_size * 4, stream);
  hipMemsetAsync(cnt, 0, 64, stream);

  cvt_x_kernel<<<4096, 256, 0, stream>>>(x, xb);
  transpose_cvt<<<dim3(16, 8, 8), 256, 0, stream>>>(w1, w1t, 512, 1024);
  transpose_cvt<<<dim3(8, 16, 8), 256, 0, stream>>>(w2, w2t, 1024, 512);

  float* logits_out = out + (size_t)T_TOK * H_DIM;
  router_logits_kernel<<<2048, 256, 0, stream>>>(x, gw, logits_out, eab, wab);
  scatter_kernel<<<32, 256, 0, stream>>>(eab, wab, cnt, tok, wgt);
  prefix_kernel<<<1, 64, 0, stream>>>(cnt, off);

  gemm1_kernel<<<dim3(512, 8), 256, 0, stream>>>(xb, w1t, b1, cnt, off, tok, h_buf);
  gemm2_kernel<<<dim3(512, 4), 256, 0, stream>>>(h_buf, w2t, b2, cnt, off, tok, wgt, out);
}